// Round 2
// baseline (214.450 us; speedup 1.0000x reference)
//
#include <hip/hip_runtime.h>
#include <hip/hip_bf16.h>

#define D 128

// ---- fold: u = W_ing @ a_src, v = W_taste @ a_dst, consts = {b_ing·a_src, b_taste·a_dst}
__global__ void fold_kernel(const float* __restrict__ W_ing, const float* __restrict__ b_ing,
                            const float* __restrict__ W_taste, const float* __restrict__ b_taste,
                            const float* __restrict__ a_src, const float* __restrict__ a_dst,
                            float* __restrict__ u, float* __restrict__ v, float* __restrict__ consts) {
    __shared__ float red[D];
    int k = threadIdx.x;  // 128 threads
    float su = 0.f, sv = 0.f;
    for (int d = 0; d < D; ++d) {
        su += W_ing[k * D + d] * a_src[d];
        sv += W_taste[k * D + d] * a_dst[d];
    }
    u[k] = su; v[k] = sv;

    red[k] = b_ing[k] * a_src[k];
    __syncthreads();
    for (int s = 64; s > 0; s >>= 1) { if (k < s) red[k] += red[k + s]; __syncthreads(); }
    if (k == 0) consts[0] = red[0];
    __syncthreads();
    red[k] = b_taste[k] * a_dst[k];
    __syncthreads();
    for (int s = 64; s > 0; s >>= 1) { if (k < s) red[k] += red[k + s]; __syncthreads(); }
    if (k == 0) consts[1] = red[0];
}

// ---- al[r] = x[r,:]·vec + c   (one wave per row, grid-stride)
__global__ __launch_bounds__(256)
void matvec_kernel(const float* __restrict__ x, const float* __restrict__ vec,
                   const float* __restrict__ cptr, int cidx, int nrows,
                   float* __restrict__ outv) {
    int lane = threadIdx.x & 63;
    int wave = blockIdx.x * (blockDim.x >> 6) + (threadIdx.x >> 6);
    int nwaves = gridDim.x * (blockDim.x >> 6);
    float2 uv = ((const float2*)vec)[lane];
    float c = cptr[cidx];
    for (int r = wave; r < nrows; r += nwaves) {
        float2 xv = ((const float2*)(x + (size_t)r * D))[lane];
        float p = xv.x * uv.x + xv.y * uv.y;
        #pragma unroll
        for (int off = 32; off; off >>= 1) p += __shfl_xor(p, off, 64);
        if (lane == 0) outv[r] = p + c;
    }
}

// ---- h = x @ W + b  (fp32 vector GEMM, 64-row tile, k-tiled 32, 24KB LDS)
__global__ __launch_bounds__(256)
void gemm_kernel(const float* __restrict__ x, const float* __restrict__ W,
                 const float* __restrict__ b, float* __restrict__ h, int nrows) {
    __shared__ float Wl[32 * D];   // 16 KB
    __shared__ float Xl[64 * 32];  // 8 KB
    int t = threadIdx.x;
    int row0 = blockIdx.x * 64;
    int cg = t & 31;   // col group of 4
    int rg = t >> 5;   // 0..7 -> rows rg*8..rg*8+7
    float acc[8][4] = {};
    for (int k0 = 0; k0 < D; k0 += 32) {
        __syncthreads();
        const float4* Wg = (const float4*)(W + k0 * D);
        #pragma unroll
        for (int i = t; i < 32 * D / 4; i += 256) ((float4*)Wl)[i] = Wg[i];
        #pragma unroll
        for (int i = t; i < 64 * 32 / 4; i += 256) {
            int r = i >> 3, c = i & 7;
            int gr = row0 + r;
            float4 val = make_float4(0.f, 0.f, 0.f, 0.f);
            if (gr < nrows) val = *(const float4*)(x + (size_t)gr * D + k0 + c * 4);
            ((float4*)Xl)[i] = val;
        }
        __syncthreads();
        #pragma unroll
        for (int kk = 0; kk < 32; ++kk) {
            float4 w4 = ((const float4*)(Wl + kk * D))[cg];
            #pragma unroll
            for (int j = 0; j < 8; ++j) {
                float xv = Xl[(rg * 8 + j) * 32 + kk];
                acc[j][0] = fmaf(xv, w4.x, acc[j][0]);
                acc[j][1] = fmaf(xv, w4.y, acc[j][1]);
                acc[j][2] = fmaf(xv, w4.z, acc[j][2]);
                acc[j][3] = fmaf(xv, w4.w, acc[j][3]);
            }
        }
    }
    float4 b4 = ((const float4*)b)[cg];
    #pragma unroll
    for (int j = 0; j < 8; ++j) {
        int gr = row0 + rg * 8 + j;
        if (gr < nrows) {
            float4 o = make_float4(acc[j][0] + b4.x, acc[j][1] + b4.y,
                                   acc[j][2] + b4.z, acc[j][3] + b4.w);
            *(float4*)(h + (size_t)gr * D + cg * 4) = o;
        }
    }
}

// ---- histogram of dst
__global__ void hist_kernel(const int* __restrict__ dstv, int E, int* __restrict__ count) {
    int stride = gridDim.x * blockDim.x;
    for (int i = blockIdx.x * blockDim.x + threadIdx.x; i < E; i += stride)
        atomicAdd(&count[dstv[i]], 1);
}

// ---- exclusive scan over count -> offs (single block, 1024 threads)
__global__ __launch_bounds__(1024)
void scan_kernel(const int* __restrict__ count, int n, int* __restrict__ offs) {
    __shared__ int buf[1024];
    __shared__ int carry_s;
    int t = threadIdx.x;
    if (t == 0) carry_s = 0;
    __syncthreads();
    for (int base = 0; base < n; base += 1024) {
        int vidx = base + t;
        int vv = (vidx < n) ? count[vidx] : 0;
        buf[t] = vv;
        __syncthreads();
        for (int off = 1; off < 1024; off <<= 1) {
            int add = (t >= off) ? buf[t - off] : 0;
            __syncthreads();
            buf[t] += add;
            __syncthreads();
        }
        int total = buf[1023];
        int carry = carry_s;
        if (vidx < n) offs[vidx] = carry + buf[t] - vv;
        __syncthreads();
        if (t == 0) carry_s = carry + total;
        __syncthreads();
    }
}

// ---- scatter edges into dst-grouped order; compute leaky-relu logits on the fly
__global__ void scatter_kernel(const int* __restrict__ srcv, const int* __restrict__ dstv, int E,
                               const float* __restrict__ al_src, const float* __restrict__ al_dst,
                               const int* __restrict__ offs, int* __restrict__ cursor,
                               int* __restrict__ srcs_s, float* __restrict__ alph_s) {
    int stride = gridDim.x * blockDim.x;
    for (int i = blockIdx.x * blockDim.x + threadIdx.x; i < E; i += stride) {
        int s = srcv[i], d = dstv[i];
        int pos = offs[d] + atomicAdd(&cursor[d], 1);
        float a = al_src[s] + al_dst[d];
        a = a > 0.f ? a : 0.2f * a;   // leaky_relu(0.2)
        srcs_s[pos] = s;
        alph_s[pos] = a;
    }
}

// ---- per-dst softmax + weighted gather-sum + relu + exact gelu, one wave per dst
// Output is FLOAT32 (reference output dtype).
__global__ __launch_bounds__(256)
void agg_kernel(const float* __restrict__ h, const int* __restrict__ offs,
                const int* __restrict__ count, const int* __restrict__ srcs_s,
                const float* __restrict__ alph_s, int nt, float* __restrict__ outp) {
    int lane = threadIdx.x & 63;
    int n = blockIdx.x * (blockDim.x >> 6) + (threadIdx.x >> 6);
    if (n >= nt) return;
    int beg = offs[n], cnt = count[n];
    float acc0 = 0.f, acc1 = 0.f;
    if (cnt > 0) {
        float m = -1e30f;
        for (int i = lane; i < cnt; i += 64) m = fmaxf(m, alph_s[beg + i]);
        #pragma unroll
        for (int off = 32; off; off >>= 1) m = fmaxf(m, __shfl_xor(m, off, 64));
        float ssum = 0.f;
        for (int i = lane; i < cnt; i += 64) ssum += expf(alph_s[beg + i] - m);
        #pragma unroll
        for (int off = 32; off; off >>= 1) ssum += __shfl_xor(ssum, off, 64);
        float inv = 1.f / fmaxf(ssum, 1e-16f);

        for (int base = 0; base < cnt; base += 64) {
            int k = cnt - base; if (k > 64) k = 64;
            float a = 0.f; int si = 0;
            if (lane < k) { a = alph_s[beg + base + lane]; si = srcs_s[beg + base + lane]; }
            float wl = expf(a - m);
            for (int i = 0; i < k; ++i) {
                float w = __shfl(wl, i, 64);
                int s2 = __shfl(si, i, 64);
                const float* hp = h + (size_t)s2 * D;
                acc0 = fmaf(w, hp[lane], acc0);
                acc1 = fmaf(w, hp[lane + 64], acc1);
            }
        }
        acc0 *= inv; acc1 *= inv;
    }
    // relu then exact gelu (beta == 1, semantic attention is identity)
    float o0 = acc0 > 0.f ? acc0 : 0.f;
    float o1 = acc1 > 0.f ? acc1 : 0.f;
    o0 = 0.5f * o0 * (1.f + erff(o0 * 0.70710678118654752f));
    o1 = 0.5f * o1 * (1.f + erff(o1 * 0.70710678118654752f));
    outp[(size_t)n * D + lane]      = o0;
    outp[(size_t)n * D + lane + 64] = o1;
}

extern "C" void kernel_launch(void* const* d_in, const int* in_sizes, int n_in,
                              void* d_out, int out_size, void* d_ws, size_t ws_size,
                              hipStream_t stream) {
    const float* x_ing   = (const float*)d_in[0];
    const float* x_taste = (const float*)d_in[1];
    const int*   edge    = (const int*)d_in[2];
    const float* W_ing   = (const float*)d_in[3];
    const float* b_ing   = (const float*)d_in[4];
    const float* W_taste = (const float*)d_in[5];
    const float* b_taste = (const float*)d_in[6];
    const float* a_src   = (const float*)d_in[7];
    const float* a_dst   = (const float*)d_in[8];
    // d_in[9..11] (Wk, bk, q) are dead: softmax over a single scalar -> beta == 1.
    float* outp = (float*)d_out;

    int Ni = in_sizes[0] / D;
    int Nt = in_sizes[1] / D;
    int E  = in_sizes[2] / 2;
    const int* srcv = edge;
    const int* dstv = edge + E;

    char* ws = (char*)d_ws;
    size_t off = 0;
    auto alloc = [&](size_t bytes) { void* p = ws + off; off += (bytes + 255) & ~(size_t)255; return p; };
    float* h      = (float*)alloc((size_t)Ni * D * 4);
    float* u      = (float*)alloc(D * 4);
    float* v      = (float*)alloc(D * 4);
    float* consts = (float*)alloc(2 * 4);
    float* al_src = (float*)alloc((size_t)Ni * 4);
    float* al_dst = (float*)alloc((size_t)Nt * 4);
    int* count    = (int*)alloc((size_t)Nt * 4);
    int* offs     = (int*)alloc((size_t)Nt * 4);
    int* cursor   = (int*)alloc((size_t)Nt * 4);
    int* srcs_s   = (int*)alloc((size_t)E * 4);
    float* alph_s = (float*)alloc((size_t)E * 4);

    hipMemsetAsync(count, 0, (size_t)Nt * 4, stream);
    hipMemsetAsync(cursor, 0, (size_t)Nt * 4, stream);

    fold_kernel<<<1, 128, 0, stream>>>(W_ing, b_ing, W_taste, b_taste, a_src, a_dst, u, v, consts);
    gemm_kernel<<<(Ni + 63) / 64, 256, 0, stream>>>(x_ing, W_ing, b_ing, h, Ni);
    matvec_kernel<<<1024, 256, 0, stream>>>(x_ing, u, consts, 0, Ni, al_src);
    matvec_kernel<<<1024, 256, 0, stream>>>(x_taste, v, consts, 1, Nt, al_dst);
    hist_kernel<<<1024, 256, 0, stream>>>(dstv, E, count);
    scan_kernel<<<1, 1024, 0, stream>>>(count, Nt, offs);
    scatter_kernel<<<1024, 256, 0, stream>>>(srcv, dstv, E, al_src, al_dst, offs, cursor, srcs_s, alph_s);
    agg_kernel<<<(Nt + 3) / 4, 256, 0, stream>>>(h, offs, count, srcs_s, alph_s, Nt, outp);
}

// Round 3
// 171.392 us; speedup vs baseline: 1.2512x; 1.2512x over previous
//
#include <hip/hip_runtime.h>
#include <hip/hip_bf16.h>

#define D 128

// ---- fold: v = W_taste @ a_dst, consts = {b_ing·a_src, b_taste·a_dst}
__global__ void fold_kernel(const float* __restrict__ b_ing,
                            const float* __restrict__ W_taste, const float* __restrict__ b_taste,
                            const float* __restrict__ a_src, const float* __restrict__ a_dst,
                            float* __restrict__ v, float* __restrict__ consts) {
    __shared__ float red[D];
    int k = threadIdx.x;  // 128 threads
    float sv = 0.f;
    for (int d = 0; d < D; ++d) sv += W_taste[k * D + d] * a_dst[d];
    v[k] = sv;

    red[k] = b_ing[k] * a_src[k];
    __syncthreads();
    for (int s = 64; s > 0; s >>= 1) { if (k < s) red[k] += red[k + s]; __syncthreads(); }
    if (k == 0) consts[0] = red[0];
    __syncthreads();
    red[k] = b_taste[k] * a_dst[k];
    __syncthreads();
    for (int s = 64; s > 0; s >>= 1) { if (k < s) red[k] += red[k + s]; __syncthreads(); }
    if (k == 0) consts[1] = red[0];
}

// ---- al[r] = x[r,:]·vec + c   (one wave per row, grid-stride) — used for al_dst only
__global__ __launch_bounds__(256)
void matvec_kernel(const float* __restrict__ x, const float* __restrict__ vec,
                   const float* __restrict__ cptr, int cidx, int nrows,
                   float* __restrict__ outv) {
    int lane = threadIdx.x & 63;
    int wave = blockIdx.x * (blockDim.x >> 6) + (threadIdx.x >> 6);
    int nwaves = gridDim.x * (blockDim.x >> 6);
    float2 uv = ((const float2*)vec)[lane];
    float c = cptr[cidx];
    for (int r = wave; r < nrows; r += nwaves) {
        float2 xv = ((const float2*)(x + (size_t)r * D))[lane];
        float p = xv.x * uv.x + xv.y * uv.y;
        #pragma unroll
        for (int off = 32; off; off >>= 1) p += __shfl_xor(p, off, 64);
        if (lane == 0) outv[r] = p + c;
    }
}

// ---- h = x @ W + b (fp32 compute, bf16 store) + fused al_src = h·a_src
// 64-row tile, k-tile 32, transposed X in LDS for b128 reads.
#define XLD 66   // padded stride for Xt: bank-conflict-free (2-way max)
__global__ __launch_bounds__(256)
void gemm_kernel(const float* __restrict__ x, const float* __restrict__ W,
                 const float* __restrict__ b, const float* __restrict__ avec,
                 const float* __restrict__ cptr,
                 ushort* __restrict__ h16, float* __restrict__ al, int nrows) {
    __shared__ float Wl[32 * D];      // 16 KB
    __shared__ float Xt[32 * XLD];    // ~8.25 KB, [kk][row] transposed
    int t = threadIdx.x;
    int row0 = blockIdx.x * 64;
    int cg = t & 31;   // col group of 4: cols cg*4..cg*4+3
    int rg = t >> 5;   // rows rg*8 .. rg*8+7
    float acc[8][4] = {};
    for (int k0 = 0; k0 < D; k0 += 32) {
        __syncthreads();
        const float4* Wg = (const float4*)(W + k0 * D);
        #pragma unroll
        for (int i = t; i < 32 * D / 4; i += 256) ((float4*)Wl)[i] = Wg[i];
        #pragma unroll
        for (int i = t; i < 64 * 32 / 4; i += 256) {
            int r = i >> 3, c = i & 7;   // c: group of 4 kk's
            int gr = row0 + r;
            float4 val = make_float4(0.f, 0.f, 0.f, 0.f);
            if (gr < nrows) val = *(const float4*)(x + (size_t)gr * D + k0 + c * 4);
            Xt[(c * 4 + 0) * XLD + r] = val.x;
            Xt[(c * 4 + 1) * XLD + r] = val.y;
            Xt[(c * 4 + 2) * XLD + r] = val.z;
            Xt[(c * 4 + 3) * XLD + r] = val.w;
        }
        __syncthreads();
        #pragma unroll
        for (int kk = 0; kk < 32; ++kk) {
            float4 w4 = ((const float4*)(Wl + kk * D))[cg];
            float4 xa = *(const float4*)(Xt + kk * XLD + rg * 8);
            float4 xb = *(const float4*)(Xt + kk * XLD + rg * 8 + 4);
            float xs[8] = {xa.x, xa.y, xa.z, xa.w, xb.x, xb.y, xb.z, xb.w};
            #pragma unroll
            for (int j = 0; j < 8; ++j) {
                acc[j][0] = fmaf(xs[j], w4.x, acc[j][0]);
                acc[j][1] = fmaf(xs[j], w4.y, acc[j][1]);
                acc[j][2] = fmaf(xs[j], w4.z, acc[j][2]);
                acc[j][3] = fmaf(xs[j], w4.w, acc[j][3]);
            }
        }
    }
    float4 b4 = ((const float4*)b)[cg];
    float4 a4 = ((const float4*)avec)[cg];
    float cconst = cptr[0];
    #pragma unroll
    for (int j = 0; j < 8; ++j) {
        int gr = row0 + rg * 8 + j;
        float h0 = acc[j][0] + b4.x, h1 = acc[j][1] + b4.y;
        float h2 = acc[j][2] + b4.z, h3 = acc[j][3] + b4.w;
        // fused al_src partial: dot my 4 cols with a_src, reduce over 32 lanes (cg)
        float p = h0 * a4.x + h1 * a4.y + h2 * a4.z + h3 * a4.w;
        #pragma unroll
        for (int off = 16; off; off >>= 1) p += __shfl_xor(p, off, 64);
        if (gr < nrows) {
            ushort4 pk;
            pk.x = __hip_bfloat16_raw(__float2bfloat16(h0)).x;
            pk.y = __hip_bfloat16_raw(__float2bfloat16(h1)).x;
            pk.z = __hip_bfloat16_raw(__float2bfloat16(h2)).x;
            pk.w = __hip_bfloat16_raw(__float2bfloat16(h3)).x;
            *(ushort4*)(h16 + (size_t)gr * D + cg * 4) = pk;
            if (cg == 0) al[gr] = p + cconst;
        }
    }
}

// ---- histogram of dst
__global__ void hist_kernel(const int* __restrict__ dstv, int E, int* __restrict__ count) {
    int stride = gridDim.x * blockDim.x;
    for (int i = blockIdx.x * blockDim.x + threadIdx.x; i < E; i += stride)
        atomicAdd(&count[dstv[i]], 1);
}

// ---- group-base allocation: wave prefix-scan + one atomic per wave.
// Offsets need only be a disjoint partition, not sorted by dst.
__global__ __launch_bounds__(256)
void alloc_kernel(const int* __restrict__ count, int n, int* __restrict__ offs,
                  int* __restrict__ total) {
    int gid = blockIdx.x * blockDim.x + threadIdx.x;
    int lane = threadIdx.x & 63;
    int v = (gid < n) ? count[gid] : 0;
    int s = v;
    #pragma unroll
    for (int off = 1; off < 64; off <<= 1) {
        int t2 = __shfl_up(s, off, 64);
        if (lane >= off) s += t2;
    }
    int wavesum = __shfl(s, 63, 64);
    int base = 0;
    if (lane == 63) base = atomicAdd(total, wavesum);
    base = __shfl(base, 63, 64);
    if (gid < n) offs[gid] = base + s - v;
}

// ---- scatter edges into dst-grouped order; compute leaky-relu logits on the fly
__global__ void scatter_kernel(const int* __restrict__ srcv, const int* __restrict__ dstv, int E,
                               const float* __restrict__ al_src, const float* __restrict__ al_dst,
                               const int* __restrict__ offs, int* __restrict__ cursor,
                               int* __restrict__ srcs_s, float* __restrict__ alph_s) {
    int stride = gridDim.x * blockDim.x;
    for (int i = blockIdx.x * blockDim.x + threadIdx.x; i < E; i += stride) {
        int s = srcv[i], d = dstv[i];
        int pos = offs[d] + atomicAdd(&cursor[d], 1);
        float a = al_src[s] + al_dst[d];
        a = a > 0.f ? a : 0.2f * a;   // leaky_relu(0.2)
        srcs_s[pos] = s;
        alph_s[pos] = a;
    }
}

// ---- per-dst softmax + weighted gather-sum (bf16 h) + relu + exact gelu
__global__ __launch_bounds__(256)
void agg_kernel(const ushort* __restrict__ h16, const int* __restrict__ offs,
                const int* __restrict__ count, const int* __restrict__ srcs_s,
                const float* __restrict__ alph_s, int nt, float* __restrict__ outp) {
    int lane = threadIdx.x & 63;
    int n = blockIdx.x * (blockDim.x >> 6) + (threadIdx.x >> 6);
    if (n >= nt) return;
    int beg = offs[n], cnt = count[n];
    float acc0 = 0.f, acc1 = 0.f;
    if (cnt > 0) {
        float m = -1e30f;
        for (int i = lane; i < cnt; i += 64) m = fmaxf(m, alph_s[beg + i]);
        #pragma unroll
        for (int off = 32; off; off >>= 1) m = fmaxf(m, __shfl_xor(m, off, 64));
        float ssum = 0.f;
        for (int i = lane; i < cnt; i += 64) ssum += __expf(alph_s[beg + i] - m);
        #pragma unroll
        for (int off = 32; off; off >>= 1) ssum += __shfl_xor(ssum, off, 64);
        float inv = 1.f / fmaxf(ssum, 1e-16f);

        for (int base = 0; base < cnt; base += 64) {
            int k = cnt - base; if (k > 64) k = 64;
            float a = 0.f; int si = 0;
            if (lane < k) { a = alph_s[beg + base + lane]; si = srcs_s[beg + base + lane]; }
            float wl = __expf(a - m);
            for (int i = 0; i < k; ++i) {
                float w = __shfl(wl, i, 64);
                int s2 = __shfl(si, i, 64);
                uint pv = ((const uint*)(h16 + (size_t)s2 * D))[lane];
                float lo = __uint_as_float((pv & 0xffffu) << 16);   // col 2*lane
                float hi = __uint_as_float(pv & 0xffff0000u);       // col 2*lane+1
                acc0 = fmaf(w, lo, acc0);
                acc1 = fmaf(w, hi, acc1);
            }
        }
        acc0 *= inv; acc1 *= inv;
    }
    float o0 = acc0 > 0.f ? acc0 : 0.f;
    float o1 = acc1 > 0.f ? acc1 : 0.f;
    o0 = 0.5f * o0 * (1.f + erff(o0 * 0.70710678118654752f));
    o1 = 0.5f * o1 * (1.f + erff(o1 * 0.70710678118654752f));
    *(float2*)(outp + (size_t)n * D + 2 * lane) = make_float2(o0, o1);
}

extern "C" void kernel_launch(void* const* d_in, const int* in_sizes, int n_in,
                              void* d_out, int out_size, void* d_ws, size_t ws_size,
                              hipStream_t stream) {
    const float* x_ing   = (const float*)d_in[0];
    const float* x_taste = (const float*)d_in[1];
    const int*   edge    = (const int*)d_in[2];
    const float* W_ing   = (const float*)d_in[3];
    const float* b_ing   = (const float*)d_in[4];
    const float* W_taste = (const float*)d_in[5];
    const float* b_taste = (const float*)d_in[6];
    const float* a_src   = (const float*)d_in[7];
    const float* a_dst   = (const float*)d_in[8];
    // d_in[9..11] (Wk, bk, q) are dead: softmax over a single scalar -> beta == 1.
    float* outp = (float*)d_out;

    int Ni = in_sizes[0] / D;
    int Nt = in_sizes[1] / D;
    int E  = in_sizes[2] / 2;
    const int* srcv = edge;
    const int* dstv = edge + E;

    char* ws = (char*)d_ws;
    size_t off = 0;
    auto alloc = [&](size_t bytes) { void* p = ws + off; off += (bytes + 255) & ~(size_t)255; return p; };
    ushort* h16   = (ushort*)alloc((size_t)Ni * D * 2);
    float* v      = (float*)alloc(D * 4);
    float* consts = (float*)alloc(2 * 4);
    float* al_src = (float*)alloc((size_t)Ni * 4);
    float* al_dst = (float*)alloc((size_t)Nt * 4);
    int* zeroed   = (int*)alloc(((size_t)2 * Nt + 1) * 4);  // count | cursor | total
    int* count    = zeroed;
    int* cursor   = zeroed + Nt;
    int* total    = zeroed + 2 * Nt;
    int* offs     = (int*)alloc((size_t)Nt * 4);
    int* srcs_s   = (int*)alloc((size_t)E * 4);
    float* alph_s = (float*)alloc((size_t)E * 4);

    hipMemsetAsync(zeroed, 0, ((size_t)2 * Nt + 1) * 4, stream);

    fold_kernel<<<1, 128, 0, stream>>>(b_ing, W_taste, b_taste, a_src, a_dst, v, consts);
    gemm_kernel<<<(Ni + 63) / 64, 256, 0, stream>>>(x_ing, W_ing, b_ing, a_src, consts,
                                                    h16, al_src, Ni);
    matvec_kernel<<<512, 256, 0, stream>>>(x_taste, v, consts, 1, Nt, al_dst);
    hist_kernel<<<1024, 256, 0, stream>>>(dstv, E, count);
    alloc_kernel<<<(Nt + 255) / 256, 256, 0, stream>>>(count, Nt, offs, total);
    scatter_kernel<<<1024, 256, 0, stream>>>(srcv, dstv, E, al_src, al_dst, offs, cursor, srcs_s, alph_s);
    agg_kernel<<<(Nt + 3) / 4, 256, 0, stream>>>(h16, offs, count, srcs_s, alph_s, Nt, outp);
}

// Round 4
// 146.955 us; speedup vs baseline: 1.4593x; 1.1663x over previous
//
#include <hip/hip_runtime.h>
#include <hip/hip_bf16.h>

#define D 128

// ---- fold: v = W_taste @ a_dst, consts = {b_ing·a_src, b_taste·a_dst}
__global__ void fold_kernel(const float* __restrict__ b_ing,
                            const float* __restrict__ W_taste, const float* __restrict__ b_taste,
                            const float* __restrict__ a_src, const float* __restrict__ a_dst,
                            float* __restrict__ v, float* __restrict__ consts) {
    __shared__ float red[D];
    int k = threadIdx.x;  // 128 threads
    float sv = 0.f;
    for (int d = 0; d < D; ++d) sv += W_taste[k * D + d] * a_dst[d];
    v[k] = sv;

    red[k] = b_ing[k] * a_src[k];
    __syncthreads();
    for (int s = 64; s > 0; s >>= 1) { if (k < s) red[k] += red[k + s]; __syncthreads(); }
    if (k == 0) consts[0] = red[0];
    __syncthreads();
    red[k] = b_taste[k] * a_dst[k];
    __syncthreads();
    for (int s = 64; s > 0; s >>= 1) { if (k < s) red[k] += red[k + s]; __syncthreads(); }
    if (k == 0) consts[1] = red[0];
}

// ---- al[r] = x[r,:]·vec + c   (one wave per row, grid-stride) — al_dst only
__global__ __launch_bounds__(256)
void matvec_kernel(const float* __restrict__ x, const float* __restrict__ vec,
                   const float* __restrict__ cptr, int cidx, int nrows,
                   float* __restrict__ outv) {
    int lane = threadIdx.x & 63;
    int wave = blockIdx.x * (blockDim.x >> 6) + (threadIdx.x >> 6);
    int nwaves = gridDim.x * (blockDim.x >> 6);
    float2 uv = ((const float2*)vec)[lane];
    float c = cptr[cidx];
    for (int r = wave; r < nrows; r += nwaves) {
        float2 xv = ((const float2*)(x + (size_t)r * D))[lane];
        float p = xv.x * uv.x + xv.y * uv.y;
        #pragma unroll
        for (int off = 32; off; off >>= 1) p += __shfl_xor(p, off, 64);
        if (lane == 0) outv[r] = p + c;
    }
}

// ---- h = x @ W + b (fp32 compute, bf16 store) + fused al_src = h·a_src
#define XLD 66
__global__ __launch_bounds__(256)
void gemm_kernel(const float* __restrict__ x, const float* __restrict__ W,
                 const float* __restrict__ b, const float* __restrict__ avec,
                 const float* __restrict__ cptr,
                 ushort* __restrict__ h16, float* __restrict__ al, int nrows) {
    __shared__ float Wl[32 * D];      // 16 KB
    __shared__ float Xt[32 * XLD];    // ~8.25 KB, [kk][row] transposed
    int t = threadIdx.x;
    int row0 = blockIdx.x * 64;
    int cg = t & 31;   // col group of 4
    int rg = t >> 5;   // rows rg*8 .. rg*8+7
    float acc[8][4] = {};
    for (int k0 = 0; k0 < D; k0 += 32) {
        __syncthreads();
        const float4* Wg = (const float4*)(W + k0 * D);
        #pragma unroll
        for (int i = t; i < 32 * D / 4; i += 256) ((float4*)Wl)[i] = Wg[i];
        #pragma unroll
        for (int i = t; i < 64 * 32 / 4; i += 256) {
            int r = i >> 3, c = i & 7;
            int gr = row0 + r;
            float4 val = make_float4(0.f, 0.f, 0.f, 0.f);
            if (gr < nrows) val = *(const float4*)(x + (size_t)gr * D + k0 + c * 4);
            Xt[(c * 4 + 0) * XLD + r] = val.x;
            Xt[(c * 4 + 1) * XLD + r] = val.y;
            Xt[(c * 4 + 2) * XLD + r] = val.z;
            Xt[(c * 4 + 3) * XLD + r] = val.w;
        }
        __syncthreads();
        #pragma unroll
        for (int kk = 0; kk < 32; ++kk) {
            float4 w4 = ((const float4*)(Wl + kk * D))[cg];
            float4 xa = *(const float4*)(Xt + kk * XLD + rg * 8);
            float4 xb = *(const float4*)(Xt + kk * XLD + rg * 8 + 4);
            float xs[8] = {xa.x, xa.y, xa.z, xa.w, xb.x, xb.y, xb.z, xb.w};
            #pragma unroll
            for (int j = 0; j < 8; ++j) {
                acc[j][0] = fmaf(xs[j], w4.x, acc[j][0]);
                acc[j][1] = fmaf(xs[j], w4.y, acc[j][1]);
                acc[j][2] = fmaf(xs[j], w4.z, acc[j][2]);
                acc[j][3] = fmaf(xs[j], w4.w, acc[j][3]);
            }
        }
    }
    float4 b4 = ((const float4*)b)[cg];
    float4 a4 = ((const float4*)avec)[cg];
    float cconst = cptr[0];
    #pragma unroll
    for (int j = 0; j < 8; ++j) {
        int gr = row0 + rg * 8 + j;
        float h0 = acc[j][0] + b4.x, h1 = acc[j][1] + b4.y;
        float h2 = acc[j][2] + b4.z, h3 = acc[j][3] + b4.w;
        float p = h0 * a4.x + h1 * a4.y + h2 * a4.z + h3 * a4.w;
        #pragma unroll
        for (int off = 16; off; off >>= 1) p += __shfl_xor(p, off, 64);
        if (gr < nrows) {
            ushort4 pk;
            pk.x = __hip_bfloat16_raw(__float2bfloat16(h0)).x;
            pk.y = __hip_bfloat16_raw(__float2bfloat16(h1)).x;
            pk.z = __hip_bfloat16_raw(__float2bfloat16(h2)).x;
            pk.w = __hip_bfloat16_raw(__float2bfloat16(h3)).x;
            *(ushort4*)(h16 + (size_t)gr * D + cg * 4) = pk;
            if (cg == 0) al[gr] = p + cconst;
        }
    }
}

// ---- histogram of dst
__global__ void hist_kernel(const int* __restrict__ dstv, int E, int* __restrict__ count) {
    int stride = gridDim.x * blockDim.x;
    for (int i = blockIdx.x * blockDim.x + threadIdx.x; i < E; i += stride)
        atomicAdd(&count[dstv[i]], 1);
}

// ---- group-base allocation: wave prefix-scan + one atomic per wave
__global__ __launch_bounds__(256)
void alloc_kernel(const int* __restrict__ count, int n, int* __restrict__ offs,
                  int* __restrict__ total) {
    int gid = blockIdx.x * blockDim.x + threadIdx.x;
    int lane = threadIdx.x & 63;
    int v = (gid < n) ? count[gid] : 0;
    int s = v;
    #pragma unroll
    for (int off = 1; off < 64; off <<= 1) {
        int t2 = __shfl_up(s, off, 64);
        if (lane >= off) s += t2;
    }
    int wavesum = __shfl(s, 63, 64);
    int base = 0;
    if (lane == 63) base = atomicAdd(total, wavesum);
    base = __shfl(base, 63, 64);
    if (gid < n) offs[gid] = base + s - v;
}

// ---- scatter edges into dst-grouped order; leaky-relu logits on the fly
__global__ void scatter_kernel(const int* __restrict__ srcv, const int* __restrict__ dstv, int E,
                               const float* __restrict__ al_src, const float* __restrict__ al_dst,
                               const int* __restrict__ offs, int* __restrict__ cursor,
                               int* __restrict__ srcs_s, float* __restrict__ alph_s) {
    int stride = gridDim.x * blockDim.x;
    for (int i = blockIdx.x * blockDim.x + threadIdx.x; i < E; i += stride) {
        int s = srcv[i], d = dstv[i];
        int pos = offs[d] + atomicAdd(&cursor[d], 1);
        float a = al_src[s] + al_dst[d];
        a = a > 0.f ? a : 0.2f * a;   // leaky_relu(0.2)
        srcs_s[pos] = s;
        alph_s[pos] = a;
    }
}

// ---- per-dst softmax + weighted gather-sum (bf16 h), 8-edge ILP, packed shfl
__global__ __launch_bounds__(256)
void agg_kernel(const ushort* __restrict__ h16, const int* __restrict__ offs,
                const int* __restrict__ count, const int* __restrict__ srcs_s,
                const float* __restrict__ alph_s, int nt, float* __restrict__ outp) {
    int lane = threadIdx.x & 63;
    int n = blockIdx.x * (blockDim.x >> 6) + (threadIdx.x >> 6);
    if (n >= nt) return;
    int beg = offs[n], cnt = count[n];
    float acc0 = 0.f, acc1 = 0.f;
    if (cnt > 0) {
        float m = -1e30f;
        for (int i = lane; i < cnt; i += 64) m = fmaxf(m, alph_s[beg + i]);
        #pragma unroll
        for (int off = 32; off; off >>= 1) m = fmaxf(m, __shfl_xor(m, off, 64));
        float ssum = 0.f;
        for (int i = lane; i < cnt; i += 64) ssum += __expf(alph_s[beg + i] - m);
        #pragma unroll
        for (int off = 32; off; off >>= 1) ssum += __shfl_xor(ssum, off, 64);
        float inv = 1.f / fmaxf(ssum, 1e-16f);

        for (int base = 0; base < cnt; base += 64) {
            int k = cnt - base; if (k > 64) k = 64;
            // pack (src<<16) | bf16(w) : src < 50000 < 2^16
            uint pkl = 0;
            if (lane < k) {
                float a = alph_s[beg + base + lane];
                int si = srcs_s[beg + base + lane];
                float w = __expf(a - m);             // in (0,1]
                uint wb = (__float_as_uint(w) + 0x8000u) >> 16;  // bf16 rne-ish
                pkl = ((uint)si << 16) | wb;
            }
            int kpad = (k + 7) & ~7;
            for (int i = 0; i < kpad; i += 8) {
                uint pk[8], hv[8];
                #pragma unroll
                for (int j = 0; j < 8; ++j) pk[j] = __shfl(pkl, i + j, 64);
                #pragma unroll
                for (int j = 0; j < 8; ++j) {
                    uint s2 = pk[j] >> 16;           // padded lanes -> row 0, w=0
                    hv[j] = ((const uint*)(h16 + (size_t)s2 * D))[lane];
                }
                #pragma unroll
                for (int j = 0; j < 8; ++j) {
                    float w  = __uint_as_float(pk[j] << 16);
                    float lo = __uint_as_float((hv[j] & 0xffffu) << 16);
                    float hi = __uint_as_float(hv[j] & 0xffff0000u);
                    acc0 = fmaf(w, lo, acc0);
                    acc1 = fmaf(w, hi, acc1);
                }
            }
        }
        acc0 *= inv; acc1 *= inv;
    }
    float o0 = acc0 > 0.f ? acc0 : 0.f;
    float o1 = acc1 > 0.f ? acc1 : 0.f;
    o0 = 0.5f * o0 * (1.f + erff(o0 * 0.70710678118654752f));
    o1 = 0.5f * o1 * (1.f + erff(o1 * 0.70710678118654752f));
    *(float2*)(outp + (size_t)n * D + 2 * lane) = make_float2(o0, o1);
}

extern "C" void kernel_launch(void* const* d_in, const int* in_sizes, int n_in,
                              void* d_out, int out_size, void* d_ws, size_t ws_size,
                              hipStream_t stream) {
    const float* x_ing   = (const float*)d_in[0];
    const float* x_taste = (const float*)d_in[1];
    const int*   edge    = (const int*)d_in[2];
    const float* W_ing   = (const float*)d_in[3];
    const float* b_ing   = (const float*)d_in[4];
    const float* W_taste = (const float*)d_in[5];
    const float* b_taste = (const float*)d_in[6];
    const float* a_src   = (const float*)d_in[7];
    const float* a_dst   = (const float*)d_in[8];
    // d_in[9..11] (Wk, bk, q) dead: softmax over single scalar -> beta == 1.
    float* outp = (float*)d_out;

    int Ni = in_sizes[0] / D;
    int Nt = in_sizes[1] / D;
    int E  = in_sizes[2] / 2;
    const int* srcv = edge;
    const int* dstv = edge + E;

    char* ws = (char*)d_ws;
    size_t off = 0;
    auto alloc = [&](size_t bytes) { void* p = ws + off; off += (bytes + 255) & ~(size_t)255; return p; };
    ushort* h16   = (ushort*)alloc((size_t)Ni * D * 2);
    float* v      = (float*)alloc(D * 4);
    float* consts = (float*)alloc(2 * 4);
    float* al_src = (float*)alloc((size_t)Ni * 4);
    float* al_dst = (float*)alloc((size_t)Nt * 4);
    int* zeroed   = (int*)alloc(((size_t)2 * Nt + 1) * 4);  // count | cursor | total
    int* count    = zeroed;
    int* cursor   = zeroed + Nt;
    int* total    = zeroed + 2 * Nt;
    int* offs     = (int*)alloc((size_t)Nt * 4);
    int* srcs_s   = (int*)alloc((size_t)E * 4);
    float* alph_s = (float*)alloc((size_t)E * 4);

    hipMemsetAsync(zeroed, 0, ((size_t)2 * Nt + 1) * 4, stream);

    fold_kernel<<<1, 128, 0, stream>>>(b_ing, W_taste, b_taste, a_src, a_dst, v, consts);
    gemm_kernel<<<(Ni + 63) / 64, 256, 0, stream>>>(x_ing, W_ing, b_ing, a_src, consts,
                                                    h16, al_src, Ni);
    matvec_kernel<<<1024, 256, 0, stream>>>(x_taste, v, consts, 1, Nt, al_dst);
    hist_kernel<<<2048, 256, 0, stream>>>(dstv, E, count);
    alloc_kernel<<<(Nt + 255) / 256, 256, 0, stream>>>(count, Nt, offs, total);
    scatter_kernel<<<2048, 256, 0, stream>>>(srcv, dstv, E, al_src, al_dst, offs, cursor, srcs_s, alph_s);
    agg_kernel<<<(Nt + 3) / 4, 256, 0, stream>>>(h16, offs, count, srcs_s, alph_s, Nt, outp);
}

// Round 5
// 123.310 us; speedup vs baseline: 1.7391x; 1.1918x over previous
//
#include <hip/hip_runtime.h>
#include <hip/hip_bf16.h>

#define D 128

using bf16x8 = __attribute__((ext_vector_type(8))) short;
using f32x4  = __attribute__((ext_vector_type(4))) float;

__device__ __forceinline__ ushort bf16bits(float f) {
    return __hip_bfloat16_raw(__float2bfloat16(f)).x;
}
__device__ __forceinline__ uint pack2(float lo, float hi) {
    return ((uint)bf16bits(hi) << 16) | (uint)bf16bits(lo);
}

// ---- prep: block0 = fold (v = W_taste@a_dst, consts); blocks1-2 = Wt = bf16(W_ing^T);
//      blocks3+ = zero count/total
__global__ __launch_bounds__(256)
void prep_kernel(const float* __restrict__ W_ing, const float* __restrict__ b_ing,
                 const float* __restrict__ W_taste, const float* __restrict__ b_taste,
                 const float* __restrict__ a_src, const float* __restrict__ a_dst,
                 ushort* __restrict__ Wt, float* __restrict__ v, float* __restrict__ consts,
                 int* __restrict__ count, int* __restrict__ total, int nt) {
    int t = threadIdx.x, b = blockIdx.x;
    if (b == 0) {
        __shared__ float red[D];
        int k = t;
        if (k < D) {
            float sv = 0.f;
            for (int d2 = 0; d2 < D; ++d2) sv += W_taste[k * D + d2] * a_dst[d2];
            v[k] = sv;
            red[k] = b_ing[k] * a_src[k];
        }
        __syncthreads();
        for (int s = 64; s > 0; s >>= 1) { if (k < s) red[k] += red[k + s]; __syncthreads(); }
        if (k == 0) consts[0] = red[0];
        __syncthreads();
        if (k < D) red[k] = b_taste[k] * a_dst[k];
        __syncthreads();
        for (int s = 64; s > 0; s >>= 1) { if (k < s) red[k] += red[k + s]; __syncthreads(); }
        if (k == 0) consts[1] = red[0];
    } else if (b <= 2) {
        int base = (b - 1) * 8192 + t * 32;
        #pragma unroll 8
        for (int i = 0; i < 32; ++i) {
            int idx = base + i;
            int n = idx >> 7, k = idx & 127;
            Wt[n * D + k] = bf16bits(W_ing[k * D + n]);
        }
    } else {
        int gid = (b - 3) * 256 + t;
        if (gid < nt) count[gid] = 0;
        if (gid == nt) *total = 0;
    }
}

// ---- MFMA GEMM: h16 = bf16(x @ W_ing + b), fused al = h·a_src + consts[0]
// block = 256 thr = 4 waves; block tile 128 rows x 128 cols; K=128.
// LDS: Xs/Ws bf16 [row][k], 16B-chunk XOR-swizzled by (row&7).
__global__ __launch_bounds__(256)
void gemm_mfma(const float* __restrict__ x, const ushort* __restrict__ Wt,
               const float* __restrict__ b, const float* __restrict__ avec,
               const float* __restrict__ consts,
               ushort* __restrict__ h16, float* __restrict__ al, int nrows) {
    __shared__ __align__(16) ushort Xs[128 * 128];
    __shared__ __align__(16) ushort Ws[128 * 128];
    int t = threadIdx.x;
    int row0 = blockIdx.x * 128;

    {   // stage X (fp32 -> bf16) and Wt (bf16), swizzled
        int r = t >> 1;
        int kh = (t & 1) * 64;            // element offset within row
        const float* xp = x + (size_t)(row0 + r) * D + kh;
        bool valid = (row0 + r) < nrows;
        const ushort* wp = Wt + (size_t)r * D + kh;
        int base_us = r * 128;
        #pragma unroll
        for (int j = 0; j < 8; ++j) {
            int c16 = (kh >> 3) + j;      // 16B chunk index 0..15
            int off = base_us + ((c16 ^ (r & 7)) << 3);
            float4 a = valid ? *(const float4*)(xp + j * 8)     : make_float4(0.f, 0.f, 0.f, 0.f);
            float4 c = valid ? *(const float4*)(xp + j * 8 + 4) : make_float4(0.f, 0.f, 0.f, 0.f);
            uint4 pk;
            pk.x = pack2(a.x, a.y); pk.y = pack2(a.z, a.w);
            pk.z = pack2(c.x, c.y); pk.w = pack2(c.z, c.w);
            *(uint4*)&Xs[off] = pk;
            *(uint4*)&Ws[off] = *(const uint4*)(wp + j * 8);
        }
    }
    __syncthreads();

    int l = t & 63, w = t >> 6;
    int lr = l & 15, lq = l >> 4;
    f32x4 acc[2][8];
    #pragma unroll
    for (int i = 0; i < 2; ++i)
        #pragma unroll
        for (int j = 0; j < 8; ++j) acc[i][j] = f32x4{0.f, 0.f, 0.f, 0.f};

    int rowA0 = w * 32 + lr;
    int rowA1 = rowA0 + 16;
    int sw = lr & 7;                       // (row&7) same for rowA0/rowA1
    #pragma unroll
    for (int s = 0; s < 4; ++s) {
        int c16 = s * 4 + lq;
        bf16x8 A0 = *(const bf16x8*)&Xs[rowA0 * 128 + ((c16 ^ sw) << 3)];
        bf16x8 A1 = *(const bf16x8*)&Xs[rowA1 * 128 + ((c16 ^ sw) << 3)];
        #pragma unroll
        for (int ct = 0; ct < 8; ++ct) {
            int rn = ct * 16 + lr;
            bf16x8 B = *(const bf16x8*)&Ws[rn * 128 + ((c16 ^ sw) << 3)];
            acc[0][ct] = __builtin_amdgcn_mfma_f32_16x16x32_bf16(A0, B, acc[0][ct], 0, 0, 0);
            acc[1][ct] = __builtin_amdgcn_mfma_f32_16x16x32_bf16(A1, B, acc[1][ct], 0, 0, 0);
        }
    }

    float bv[8], av[8];
    #pragma unroll
    for (int ct = 0; ct < 8; ++ct) { bv[ct] = b[ct * 16 + lr]; av[ct] = avec[ct * 16 + lr]; }
    float c0 = consts[0];
    #pragma unroll
    for (int rt = 0; rt < 2; ++rt) {
        #pragma unroll
        for (int r = 0; r < 4; ++r) {
            int gr = row0 + w * 32 + rt * 16 + lq * 4 + r;
            float p = 0.f;
            ushort hrow[8];
            #pragma unroll
            for (int ct = 0; ct < 8; ++ct) {
                float hv = acc[rt][ct][r] + bv[ct];
                p = fmaf(hv, av[ct], p);
                hrow[ct] = bf16bits(hv);
            }
            p += __shfl_xor(p, 1, 64); p += __shfl_xor(p, 2, 64);
            p += __shfl_xor(p, 4, 64); p += __shfl_xor(p, 8, 64);
            if (gr < nrows) {
                #pragma unroll
                for (int ct = 0; ct < 8; ++ct)
                    h16[(size_t)gr * D + ct * 16 + lr] = hrow[ct];
                if (lr == 0) al[gr] = p + c0;
            }
        }
    }
}

// ---- fused: blocks [0,512) = al_dst matvec; blocks [512,2048) = dst histogram
__global__ __launch_bounds__(256)
void mh_kernel(const float* __restrict__ x_taste, const float* __restrict__ v,
               const float* __restrict__ consts, int nt, float* __restrict__ al_dst,
               const int* __restrict__ dstv, int E, int* __restrict__ count) {
    if (blockIdx.x < 512) {
        int lane = threadIdx.x & 63;
        int wave = blockIdx.x * 4 + (threadIdx.x >> 6);
        float2 uv = ((const float2*)v)[lane];
        float c = consts[1];
        for (int r = wave; r < nt; r += 2048) {
            float2 xv = ((const float2*)(x_taste + (size_t)r * D))[lane];
            float p = xv.x * uv.x + xv.y * uv.y;
            #pragma unroll
            for (int off = 32; off; off >>= 1) p += __shfl_xor(p, off, 64);
            if (lane == 0) al_dst[r] = p + c;
        }
    } else {
        int idx0 = (blockIdx.x - 512) * 256 + threadIdx.x;
        for (int i = idx0; i < E; i += 1536 * 256)
            atomicAdd(&count[dstv[i]], 1);
    }
}

// ---- group-base allocation: wave prefix-scan + one atomic per wave; cursor = offs copy
__global__ __launch_bounds__(256)
void alloc_kernel(const int* __restrict__ count, int n, int* __restrict__ offs,
                  int* __restrict__ cursor, int* __restrict__ total) {
    int gid = blockIdx.x * blockDim.x + threadIdx.x;
    int lane = threadIdx.x & 63;
    int v = (gid < n) ? count[gid] : 0;
    int s = v;
    #pragma unroll
    for (int off = 1; off < 64; off <<= 1) {
        int t2 = __shfl_up(s, off, 64);
        if (lane >= off) s += t2;
    }
    int wavesum = __shfl(s, 63, 64);
    int base = 0;
    if (lane == 63) base = atomicAdd(total, wavesum);
    base = __shfl(base, 63, 64);
    if (gid < n) { int o = base + s - v; offs[gid] = o; cursor[gid] = o; }
}

// ---- scatter edges into dst-grouped order; one packed 8B record per edge
__global__ void scatter_kernel(const int* __restrict__ srcv, const int* __restrict__ dstv, int E,
                               const float* __restrict__ al_src, const float* __restrict__ al_dst,
                               int* __restrict__ cursor, uint2* __restrict__ es) {
    int stride = gridDim.x * blockDim.x;
    for (int i = blockIdx.x * blockDim.x + threadIdx.x; i < E; i += stride) {
        int s = srcv[i], d = dstv[i];
        int pos = atomicAdd(&cursor[d], 1);
        float a = al_src[s] + al_dst[d];
        a = a > 0.f ? a : 0.2f * a;   // leaky_relu(0.2)
        es[pos] = make_uint2((uint)s, __float_as_uint(a));
    }
}

// ---- per-dst softmax + weighted gather-sum (bf16 h), 8-edge ILP, packed shfl
__global__ __launch_bounds__(256)
void agg_kernel(const ushort* __restrict__ h16, const int* __restrict__ offs,
                const int* __restrict__ count, const uint2* __restrict__ es,
                int nt, float* __restrict__ outp) {
    int lane = threadIdx.x & 63;
    int n = blockIdx.x * (blockDim.x >> 6) + (threadIdx.x >> 6);
    if (n >= nt) return;
    int beg = offs[n], cnt = count[n];
    float acc0 = 0.f, acc1 = 0.f;
    if (cnt > 0) {
        float m = -1e30f;
        for (int i = lane; i < cnt; i += 64) m = fmaxf(m, __uint_as_float(es[beg + i].y));
        #pragma unroll
        for (int off = 32; off; off >>= 1) m = fmaxf(m, __shfl_xor(m, off, 64));
        float ssum = 0.f;
        for (int i = lane; i < cnt; i += 64) ssum += __expf(__uint_as_float(es[beg + i].y) - m);
        #pragma unroll
        for (int off = 32; off; off >>= 1) ssum += __shfl_xor(ssum, off, 64);
        float inv = 1.f / fmaxf(ssum, 1e-16f);

        for (int base = 0; base < cnt; base += 64) {
            int k = cnt - base; if (k > 64) k = 64;
            uint pkl = 0;
            if (lane < k) {
                uint2 e = es[beg + base + lane];
                float wv = __expf(__uint_as_float(e.y) - m);   // (0,1]
                uint wb = (__float_as_uint(wv) + 0x8000u) >> 16;
                pkl = (e.x << 16) | wb;
            }
            int kpad = (k + 7) & ~7;
            for (int i = 0; i < kpad; i += 8) {
                uint pk[8], hv[8];
                #pragma unroll
                for (int j = 0; j < 8; ++j) pk[j] = __shfl(pkl, i + j, 64);
                #pragma unroll
                for (int j = 0; j < 8; ++j) {
                    uint s2 = pk[j] >> 16;         // padded lanes -> row 0, w=0
                    hv[j] = ((const uint*)(h16 + (size_t)s2 * D))[lane];
                }
                #pragma unroll
                for (int j = 0; j < 8; ++j) {
                    float w  = __uint_as_float(pk[j] << 16);
                    float lo = __uint_as_float((hv[j] & 0xffffu) << 16);
                    float hi = __uint_as_float(hv[j] & 0xffff0000u);
                    acc0 = fmaf(w, lo, acc0);
                    acc1 = fmaf(w, hi, acc1);
                }
            }
        }
        acc0 *= inv; acc1 *= inv;
    }
    float o0 = acc0 > 0.f ? acc0 : 0.f;
    float o1 = acc1 > 0.f ? acc1 : 0.f;
    o0 = 0.5f * o0 * (1.f + erff(o0 * 0.70710678118654752f));
    o1 = 0.5f * o1 * (1.f + erff(o1 * 0.70710678118654752f));
    *(float2*)(outp + (size_t)n * D + 2 * lane) = make_float2(o0, o1);
}

extern "C" void kernel_launch(void* const* d_in, const int* in_sizes, int n_in,
                              void* d_out, int out_size, void* d_ws, size_t ws_size,
                              hipStream_t stream) {
    const float* x_ing   = (const float*)d_in[0];
    const float* x_taste = (const float*)d_in[1];
    const int*   edge    = (const int*)d_in[2];
    const float* W_ing   = (const float*)d_in[3];
    const float* b_ing   = (const float*)d_in[4];
    const float* W_taste = (const float*)d_in[5];
    const float* b_taste = (const float*)d_in[6];
    const float* a_src   = (const float*)d_in[7];
    const float* a_dst   = (const float*)d_in[8];
    // d_in[9..11] (Wk, bk, q) dead: softmax over single scalar -> beta == 1.
    float* outp = (float*)d_out;

    int Ni = in_sizes[0] / D;
    int Nt = in_sizes[1] / D;
    int E  = in_sizes[2] / 2;
    const int* srcv = edge;
    const int* dstv = edge + E;

    char* ws = (char*)d_ws;
    size_t off = 0;
    auto alloc = [&](size_t bytes) { void* p = ws + off; off += (bytes + 255) & ~(size_t)255; return p; };
    ushort* h16   = (ushort*)alloc((size_t)Ni * D * 2);
    ushort* Wt    = (ushort*)alloc((size_t)D * D * 2);
    float* v      = (float*)alloc(D * 4);
    float* consts = (float*)alloc(2 * 4);
    float* al_src = (float*)alloc((size_t)Ni * 4);
    float* al_dst = (float*)alloc((size_t)Nt * 4);
    int* count    = (int*)alloc((size_t)Nt * 4);
    int* offs     = (int*)alloc((size_t)Nt * 4);
    int* cursor   = (int*)alloc((size_t)Nt * 4);
    int* total    = (int*)alloc(4);
    uint2* es     = (uint2*)alloc((size_t)E * 8);

    int zb = (Nt + 1 + 255) / 256;   // blocks to zero count+total
    prep_kernel<<<3 + zb, 256, 0, stream>>>(W_ing, b_ing, W_taste, b_taste, a_src, a_dst,
                                            Wt, v, consts, count, total, Nt);
    gemm_mfma<<<(Ni + 127) / 128, 256, 0, stream>>>(x_ing, Wt, b_ing, a_src, consts,
                                                    h16, al_src, Ni);
    mh_kernel<<<2048, 256, 0, stream>>>(x_taste, v, consts, Nt, al_dst, dstv, E, count);
    alloc_kernel<<<(Nt + 255) / 256, 256, 0, stream>>>(count, Nt, offs, cursor, total);
    scatter_kernel<<<2048, 256, 0, stream>>>(srcv, dstv, E, al_src, al_dst, cursor, es);
    agg_kernel<<<(Nt + 3) / 4, 256, 0, stream>>>(h16, offs, count, es, Nt, outp);
}